// Round 6
// baseline (866.445 us; speedup 1.0000x reference)
//
#include <hip/hip_runtime.h>
#include <math.h>

using u16 = unsigned short;
using bf16x8 = __attribute__((ext_vector_type(8))) short;
using f32x4  = __attribute__((ext_vector_type(4))) float;

#define DEV static __device__ __forceinline__

DEV u16 f2bf(float f) {
  union { float f; unsigned u; } v; v.f = f;
  unsigned u = v.u + 0x7fffu + ((v.u >> 16) & 1u);
  return (u16)(u >> 16);
}

DEV void gload16(const void* g, void* l) {
  __builtin_amdgcn_global_load_lds(
      (const __attribute__((address_space(1))) void*)g,
      (__attribute__((address_space(3))) void*)l, 16, 0, 0);
}

// ---------------- prep kernels ----------------
__global__ void k_conv_bf16(const float* __restrict__ in, u16* __restrict__ out, int n) {
  int i = blockIdx.x * 256 + threadIdx.x;
  if (i < n) out[i] = f2bf(in[i]);
}

// in: f32 [K][Nin] row-major ; out: bf16 [Nout][K] (n-major).
// pack==1: n' = d2*48+j maps to n = d2*47+j for j<47, j==47 -> 0 (pad).
__global__ void k_transconv(const float* __restrict__ in, u16* __restrict__ out,
                            int K, int Nin, int Nout, int pack) {
  __shared__ float t[32][33];
  int kb = blockIdx.x * 32, nb = blockIdx.y * 32;
  int tx = threadIdx.x & 31, ty = threadIdx.x >> 5;  // 32 x 8
  #pragma unroll
  for (int i = 0; i < 4; ++i) {
    int k = kb + ty + i * 8;
    int no = nb + tx;
    float v = 0.f;
    if (k < K && no < Nout) {
      if (pack) {
        int r = no % 48;
        if (r < 47) v = in[(size_t)k * Nin + (no / 48) * 47 + r];
      } else {
        v = in[(size_t)k * Nin + no];
      }
    }
    t[ty + i * 8][tx] = v;
  }
  __syncthreads();
  #pragma unroll
  for (int i = 0; i < 4; ++i) {
    int no = nb + ty + i * 8;
    int k = kb + tx;
    if (no < Nout && k < K) out[(size_t)no * K + k] = f2bf(t[tx][ty + i * 8]);
  }
}

// ---------------- GEMM + ReLU (BM=128,BN=128,BK=32, 4 waves) for GEMM1/2 ----------------
__global__ __launch_bounds__(256)
void k_gemm_relu(const u16* __restrict__ A, const u16* __restrict__ Bt,
                 const float* __restrict__ bias, u16* __restrict__ C,
                 int N, int K) {
  constexpr int BM = 128, BN = 128, BK = 32;
  __shared__ __align__(16) u16 lds[(BM + BN) * BK];
  int tid = threadIdx.x, w = tid >> 6, lane = tid & 63;
  int bn = blockIdx.x, bm = blockIdx.y;
  int brow = bm * BM, bcol = bn * BN;
  int wm = w >> 1, wn = w & 1;
  int fr = lane & 15, fg = lane >> 4;
  f32x4 acc[4][4];
  #pragma unroll
  for (int i = 0; i < 4; ++i)
    #pragma unroll
    for (int j = 0; j < 4; ++j) acc[i][j] = (f32x4){0.f, 0.f, 0.f, 0.f};

  constexpr int ACH = BM * BK / 8;
  constexpr int CALLS = (BM + BN) * BK / 8 / 64;

  for (int kt = 0; kt < K; kt += BK) {
    for (int j = 0; j * 4 + w < CALLS; ++j) {
      int cb = (j * 4 + w) * 64;
      int c = cb + lane;
      const u16* g;
      if (c < ACH) {
        int row = c >> 2, c8 = c & 3;
        g = A + (size_t)(brow + row) * K + kt + c8 * 8;
      } else {
        int b = c - ACH;
        int nn = b >> 2, c8 = b & 3;
        g = Bt + (size_t)(bcol + nn) * K + kt + c8 * 8;
      }
      gload16(g, &lds[cb * 8]);
    }
    asm volatile("s_waitcnt vmcnt(0)" ::: "memory");
    __syncthreads();

    const u16* Al = lds;
    const u16* Bl = lds + BM * BK;
    bf16x8 af[4], bfr[4];
    #pragma unroll
    for (int mi = 0; mi < 4; ++mi)
      af[mi] = *(const bf16x8*)&Al[(wm * 64 + mi * 16 + fr) * BK + fg * 8];
    #pragma unroll
    for (int ni = 0; ni < 4; ++ni)
      bfr[ni] = *(const bf16x8*)&Bl[(wn * 64 + ni * 16 + fr) * BK + fg * 8];
    #pragma unroll
    for (int mi = 0; mi < 4; ++mi)
      #pragma unroll
      for (int ni = 0; ni < 4; ++ni)
        acc[mi][ni] = __builtin_amdgcn_mfma_f32_16x16x32_bf16(af[mi], bfr[ni], acc[mi][ni], 0, 0, 0);
    __syncthreads();
  }

  #pragma unroll
  for (int ni = 0; ni < 4; ++ni) {
    int col = bcol + wn * 64 + ni * 16 + fr;
    float bb = bias[col];
    #pragma unroll
    for (int mi = 0; mi < 4; ++mi) {
      #pragma unroll
      for (int q = 0; q < 4; ++q) {
        int row = brow + wm * 64 + mi * 16 + fg * 4 + q;
        float vv = acc[mi][ni][q] + bb;
        C[(size_t)row * N + col] = f2bf(vv > 0.f ? vv : 0.f);
      }
    }
  }
}

// ------- GEMM3 fused with spline: BM=256, BN=192, BK=32, 8 waves, 2 blocks/CU -------
// LDS 57344 B: A dbuf 2x16384 ([256][32] bf16, chunk-XOR swizzled) at 0;
// B dbuf 2x12288 ([192][32]) at 32768. Epilogue aliases: 4 slots [64][49] f32
// (50176 B) + ldacc [256][4] f32 at 50176.
// Simple m97-style loop: issue next tile's 7 loads (A: 2/thread; B: 2/thread for
// waves 0-5), compute 24 MFMA/wave, vmcnt(0)+barrier. Cross-block overlap at
// 2 blocks/CU covers the drain (m97/m114 mechanism).
__global__ __launch_bounds__(512, 4)
void k_gemm3_fused(const u16* __restrict__ A, const u16* __restrict__ Bt,
                   const float* __restrict__ b2, const float* __restrict__ x2,
                   float* __restrict__ y2, float* __restrict__ ldpart) {
  extern __shared__ char smem[];
  const int tid = threadIdx.x, w = tid >> 6, lane = tid & 63;
  const int wm = w >> 2, wn = w & 3;
  const int fr = lane & 15, fg = lane >> 4;

  const int bid = blockIdx.x;
  const int bm = bid >> 6;
  const int bn = ((bid & 7) << 3) | ((bid >> 3) & 7);
  const int brow = bm * 256;

  // staging: rows of 64B = 4 chunks of 16B. thread covers (row=tid>>2, chunk=tid&3),
  // plus row+128 (A) / row+96 (B). Source chunk pre-XOR'd: csrc = c ^ (row&3)
  // ((row+128)&3 == (row+96)&3 == row&3). LDS dest linear = tid*16 (rule #21).
  const int csrc = (tid & 3) ^ ((tid >> 2) & 3);
  const u16* gA0 = A + (size_t)(brow + (tid >> 2)) * 1024 + csrc * 8;
  const u16* gB0 = Bt + (size_t)(bn * 192 + (tid >> 2)) * 1024 + csrc * 8;

#define ISSUE_ALL(t1) {                                              \
    const size_t ko_ = (size_t)(t1) * 32;                            \
    char* pa_ = smem + ((t1) & 1) * 16384;                           \
    char* pb_ = smem + 32768 + ((t1) & 1) * 12288;                   \
    gload16(gA0 + ko_, pa_ + tid * 16);                              \
    gload16(gA0 + 131072 + ko_, pa_ + tid * 16 + 8192);              \
    if (w < 6) {                                                     \
      gload16(gB0 + ko_, pb_ + tid * 16);                            \
      gload16(gB0 + 98304 + ko_, pb_ + tid * 16 + 6144);             \
    } }

  // swizzled read chunk offset (bytes): chunk = fg ^ (row&3), row&3 == fr&3
  const int sc = ((fg ^ (fr & 3)) << 4);

  f32x4 acc[8][3];
  #pragma unroll
  for (int m = 0; m < 8; ++m)
    #pragma unroll
    for (int n = 0; n < 3; ++n) acc[m][n] = (f32x4){0.f, 0.f, 0.f, 0.f};

  ISSUE_ALL(0);
  asm volatile("s_waitcnt vmcnt(0)" ::: "memory");
  __syncthreads();

  for (int t = 0; t < 32; ++t) {
    if (t < 31) ISSUE_ALL(t + 1);
    const char* Ab = smem + (t & 1) * 16384;
    const char* Bb = smem + 32768 + (t & 1) * 12288;
    bf16x8 b[3];
    #pragma unroll
    for (int n = 0; n < 3; ++n)
      b[n] = *(const bf16x8*)(Bb + (wn * 48 + n * 16 + fr) * 64 + sc);
    __builtin_amdgcn_s_setprio(1);
    #pragma unroll
    for (int m = 0; m < 8; ++m) {
      bf16x8 a = *(const bf16x8*)(Ab + (wm * 128 + m * 16 + fr) * 64 + sc);
      #pragma unroll
      for (int n = 0; n < 3; ++n)
        acc[m][n] = __builtin_amdgcn_mfma_f32_16x16x32_bf16(a, b[n], acc[m][n], 0, 0, 0);
    }
    __builtin_amdgcn_s_setprio(0);
    asm volatile("s_waitcnt vmcnt(0)" ::: "memory");
    __syncthreads();
  }

  // ---- epilogue: 4 rounds (W=wm-half, rh=row-half); slots 4x[64][49] f32 ----
  float* ldacc = (float*)(smem + 50176);  // [256][4]
  #pragma unroll
  for (int round = 0; round < 4; ++round) {
    const int W = round >> 1, rh = round & 1;
    if (wm == W) {
      float* slot = (float*)(smem + wn * 12544);
      #pragma unroll
      for (int mm = 0; mm < 4; ++mm)
        #pragma unroll
        for (int n = 0; n < 3; ++n)
          #pragma unroll
          for (int q = 0; q < 4; ++q)
            slot[(mm * 16 + fg * 4 + q) * 49 + n * 16 + fr] = acc[rh * 4 + mm][n][q];
    }
    __syncthreads();
    if (tid < 256) {
      const int grp = tid >> 6, r = tid & 63;
      const float* pr = (const float*)(smem + grp * 12544) + r * 49;
      const int grow = brow + W * 128 + rh * 64 + r;
      const int d2 = bn * 4 + grp;
      const float* bb = b2 + (size_t)d2 * 47;

      float wv[16], hv[16];
      #pragma unroll
      for (int j = 0; j < 16; ++j) wv[j] = pr[j] + bb[j];
      #pragma unroll
      for (int j = 0; j < 16; ++j) hv[j] = pr[16 + j] + bb[16 + j];

      float x = x2[(size_t)grow * 256 + d2];
      float xc = fminf(fmaxf(x, -3.f), 3.f);

      float mw = wv[0];
      #pragma unroll
      for (int j = 1; j < 16; ++j) mw = fmaxf(mw, wv[j]);
      float sw = 0.f;
      #pragma unroll
      for (int j = 0; j < 16; ++j) { wv[j] = __expf(wv[j] - mw); sw += wv[j]; }
      float scw = 0.984f / sw;

      float mh = hv[0];
      #pragma unroll
      for (int j = 1; j < 16; ++j) mh = fmaxf(mh, hv[j]);
      float sh = 0.f;
      #pragma unroll
      for (int j = 0; j < 16; ++j) { hv[j] = __expf(hv[j] - mh); sh += hv[j]; }
      float sch = 0.984f / sh;

      int idx = 0;
      float xk = -3.f, cum = 0.f;
      #pragma unroll
      for (int i = 1; i <= 15; ++i) {
        cum += 0.001f + wv[i - 1] * scw;
        float cwi = 6.f * cum - 3.f;
        if (xc >= cwi) { idx = i; xk = cwi; }
      }
      float yk = -3.f, cumh = 0.f;
      #pragma unroll
      for (int i = 1; i <= 15; ++i) {
        cumh += 0.001f + hv[i - 1] * sch;
        float chi = 6.f * cumh - 3.f;
        if (i == idx) yk = chi;
      }
      float wk = 1.f, hk = 1.f;
      #pragma unroll
      for (int i = 0; i < 16; ++i) {
        if (i == idx) {
          wk = 6.f * (0.001f + wv[i] * scw);
          hk = 6.f * (0.001f + hv[i] * sch);
        }
      }
      float dk = 1.f, dk1 = 1.f;
      #pragma unroll
      for (int i = 1; i <= 15; ++i) {
        float u = pr[32 + i - 1] + bb[32 + i - 1];
        float e = __expf(u);
        float dd = 0.001f + (u > 15.f ? u : log1pf(e));
        if (i == idx) dk = dd;
        if (i == idx + 1) dk1 = dd;
      }

      float sk = hk / wk;
      float th = (xc - xk) / wk;
      float om = 1.f - th;
      float t1m = th * om;
      float den = sk + (dk + dk1 - 2.f * sk) * t1m;
      float y = yk + hk * (sk * th * th + dk * t1m) / den;
      float deriv = sk * sk * (dk1 * th * th + 2.f * sk * t1m + dk * om * om) / (den * den);
      bool inside = (x > -3.f) && (x < 3.f);
      float yout = inside ? y : x;
      float ld = inside ? __logf(deriv) : 0.f;

      y2[(size_t)grow * 256 + d2] = yout;
      ldacc[(W * 128 + rh * 64 + r) * 4 + grp] = ld;
    }
    __syncthreads();
  }

  if (tid < 256) {
    float s = ldacc[tid * 4] + ldacc[tid * 4 + 1] + ldacc[tid * 4 + 2] + ldacc[tid * 4 + 3];
    ldpart[(size_t)bn * 16384 + brow + tid] = s;
  }
}

__global__ void k_reduce_ld(const float* __restrict__ part, float* __restrict__ out) {
  int r = blockIdx.x * 256 + threadIdx.x;
  float s = 0.f;
  for (int j = 0; j < 64; ++j) s += part[(size_t)j * 16384 + r];
  out[r] = s;
}

// ---------------- launch ----------------
extern "C" void kernel_launch(void* const* d_in, const int* in_sizes, int n_in,
                              void* d_out, int out_size, void* d_ws, size_t ws_size,
                              hipStream_t stream) {
  const float* x1 = (const float*)d_in[0];
  const float* x2 = (const float*)d_in[1];
  const float* W0 = (const float*)d_in[2];
  const float* b0 = (const float*)d_in[3];
  const float* W1 = (const float*)d_in[4];
  const float* b1 = (const float*)d_in[5];
  const float* W2 = (const float*)d_in[6];
  const float* b2 = (const float*)d_in[7];
  float* y2 = (float*)d_out;
  float* logdet = y2 + (size_t)16384 * 256;

  char* ws = (char*)d_ws;
  u16* W2t = (u16*)ws;                                   // 25165824
  u16* W0t = (u16*)(ws + 25165824);                      //   524288
  u16* W1t = (u16*)(ws + 25165824 + 524288);             //  2097152
  u16* x1b = (u16*)(ws + 27787264);                      //  8388608
  float* ldp = (float*)(ws + 27787264);                  // aliases x1b (dead by GEMM3); 64*16384*4=4MB
  u16* h1  = (u16*)(ws + 36175872);                      // 33554432
  u16* h2  = (u16*)(ws + 69730304);                      // 33554432

  hipFuncSetAttribute((const void*)k_gemm3_fused,
                      hipFuncAttributeMaxDynamicSharedMemorySize, 57344);

  k_conv_bf16<<<16384, 256, 0, stream>>>(x1, x1b, 16384 * 256);
  k_transconv<<<dim3(8, 32), 256, 0, stream>>>(W0, W0t, 256, 1024, 1024, 0);
  k_transconv<<<dim3(32, 32), 256, 0, stream>>>(W1, W1t, 1024, 1024, 1024, 0);
  k_transconv<<<dim3(32, 384), 256, 0, stream>>>(W2, W2t, 1024, 12032, 12288, 1);

  k_gemm_relu<<<dim3(8, 128), 256, 0, stream>>>(x1b, W0t, b0, h1, 1024, 256);
  k_gemm_relu<<<dim3(8, 128), 256, 0, stream>>>(h1, W1t, b1, h2, 1024, 1024);
  k_gemm3_fused<<<4096, 512, 57344, stream>>>(h2, W2t, b2, x2, y2, ldp);
  k_reduce_ld<<<64, 256, 0, stream>>>(ldp, logdet);
}

// Round 7
// 736.436 us; speedup vs baseline: 1.1765x; 1.1765x over previous
//
#include <hip/hip_runtime.h>
#include <math.h>

using u16 = unsigned short;
using bf16x8 = __attribute__((ext_vector_type(8))) short;
using f32x4  = __attribute__((ext_vector_type(4))) float;

#define DEV static __device__ __forceinline__

DEV u16 f2bf(float f) {
  union { float f; unsigned u; } v; v.f = f;
  unsigned u = v.u + 0x7fffu + ((v.u >> 16) & 1u);
  return (u16)(u >> 16);
}

DEV void gload16(const void* g, void* l) {
  __builtin_amdgcn_global_load_lds(
      (const __attribute__((address_space(1))) void*)g,
      (__attribute__((address_space(3))) void*)l, 16, 0, 0);
}

// ---------------- prep kernels ----------------
__global__ void k_conv_bf16(const float* __restrict__ in, u16* __restrict__ out, int n) {
  int i = blockIdx.x * 256 + threadIdx.x;
  if (i < n) out[i] = f2bf(in[i]);
}

// in: f32 [K][Nin] row-major ; out: bf16 [Nout][K] (n-major).
// pack==1: n' = d2*48+j maps to n = d2*47+j for j<47, j==47 -> 0 (pad).
__global__ void k_transconv(const float* __restrict__ in, u16* __restrict__ out,
                            int K, int Nin, int Nout, int pack) {
  __shared__ float t[32][33];
  int kb = blockIdx.x * 32, nb = blockIdx.y * 32;
  int tx = threadIdx.x & 31, ty = threadIdx.x >> 5;  // 32 x 8
  #pragma unroll
  for (int i = 0; i < 4; ++i) {
    int k = kb + ty + i * 8;
    int no = nb + tx;
    float v = 0.f;
    if (k < K && no < Nout) {
      if (pack) {
        int r = no % 48;
        if (r < 47) v = in[(size_t)k * Nin + (no / 48) * 47 + r];
      } else {
        v = in[(size_t)k * Nin + no];
      }
    }
    t[ty + i * 8][tx] = v;
  }
  __syncthreads();
  #pragma unroll
  for (int i = 0; i < 4; ++i) {
    int no = nb + ty + i * 8;
    int k = kb + tx;
    if (no < Nout && k < K) out[(size_t)no * K + k] = f2bf(t[tx][ty + i * 8]);
  }
}

// ---------------- GEMM + ReLU (BM=128,BN=128,BK=32, 4 waves) for GEMM1/2 ----------------
__global__ __launch_bounds__(256)
void k_gemm_relu(const u16* __restrict__ A, const u16* __restrict__ Bt,
                 const float* __restrict__ bias, u16* __restrict__ C,
                 int N, int K) {
  constexpr int BM = 128, BN = 128, BK = 32;
  __shared__ __align__(16) u16 lds[(BM + BN) * BK];
  int tid = threadIdx.x, w = tid >> 6, lane = tid & 63;
  int bn = blockIdx.x, bm = blockIdx.y;
  int brow = bm * BM, bcol = bn * BN;
  int wm = w >> 1, wn = w & 1;
  int fr = lane & 15, fg = lane >> 4;
  f32x4 acc[4][4];
  #pragma unroll
  for (int i = 0; i < 4; ++i)
    #pragma unroll
    for (int j = 0; j < 4; ++j) acc[i][j] = (f32x4){0.f, 0.f, 0.f, 0.f};

  constexpr int ACH = BM * BK / 8;
  constexpr int CALLS = (BM + BN) * BK / 8 / 64;

  for (int kt = 0; kt < K; kt += BK) {
    for (int j = 0; j * 4 + w < CALLS; ++j) {
      int cb = (j * 4 + w) * 64;
      int c = cb + lane;
      const u16* g;
      if (c < ACH) {
        int row = c >> 2, c8 = c & 3;
        g = A + (size_t)(brow + row) * K + kt + c8 * 8;
      } else {
        int b = c - ACH;
        int nn = b >> 2, c8 = b & 3;
        g = Bt + (size_t)(bcol + nn) * K + kt + c8 * 8;
      }
      gload16(g, &lds[cb * 8]);
    }
    asm volatile("s_waitcnt vmcnt(0)" ::: "memory");
    __syncthreads();

    const u16* Al = lds;
    const u16* Bl = lds + BM * BK;
    bf16x8 af[4], bfr[4];
    #pragma unroll
    for (int mi = 0; mi < 4; ++mi)
      af[mi] = *(const bf16x8*)&Al[(wm * 64 + mi * 16 + fr) * BK + fg * 8];
    #pragma unroll
    for (int ni = 0; ni < 4; ++ni)
      bfr[ni] = *(const bf16x8*)&Bl[(wn * 64 + ni * 16 + fr) * BK + fg * 8];
    #pragma unroll
    for (int mi = 0; mi < 4; ++mi)
      #pragma unroll
      for (int ni = 0; ni < 4; ++ni)
        acc[mi][ni] = __builtin_amdgcn_mfma_f32_16x16x32_bf16(af[mi], bfr[ni], acc[mi][ni], 0, 0, 0);
    __syncthreads();
  }

  #pragma unroll
  for (int ni = 0; ni < 4; ++ni) {
    int col = bcol + wn * 64 + ni * 16 + fr;
    float bb = bias[col];
    #pragma unroll
    for (int mi = 0; mi < 4; ++mi) {
      #pragma unroll
      for (int q = 0; q < 4; ++q) {
        int row = brow + wm * 64 + mi * 16 + fg * 4 + q;
        float vv = acc[mi][ni][q] + bb;
        C[(size_t)row * N + col] = f2bf(vv > 0.f ? vv : 0.f);
      }
    }
  }
}

// ------- GEMM3 fused with spline: BM=128, BN=192, BK=64, 4 waves, 2 blocks/CU -------
// LDS 81920 B: A dbuf 2x16384 ([128][64] bf16, R3-proven XOR swizzle) at 0;
// B dbuf 2x24576 ([192][64]) at 32768. Epilogue aliases: 4 slots [64][49] f32
// (50176 B) + ldacc [128][4] f32 at 50176.
// Per-wave output 64x96 (M_rep=4, N_rep=6): 20 ds_read_b128 feed 48 MFMA/tile.
// Simple schedule: issue all 10 next-tile gload16 at tile top (full-tile lead),
// one vmcnt(0)+barrier at tile end; 2 blocks/CU give cross-block overlap.
__global__ __launch_bounds__(256, 2)
void k_gemm3_fused(const u16* __restrict__ A, const u16* __restrict__ Bt,
                   const float* __restrict__ b2, const float* __restrict__ x2,
                   float* __restrict__ y2, float* __restrict__ ldpart) {
  extern __shared__ char smem[];
  const int tid = threadIdx.x, w = tid >> 6, lane = tid & 63;
  const int wm = w >> 1, wn = w & 1;
  const int fr = lane & 15, fg = lane >> 4;

  const int bid = blockIdx.x;                     // 8192 blocks
  const int bm = bid >> 6;                        // 0..127
  const int bn = ((bid & 7) << 3) | ((bid >> 3) & 7);  // 0..63, XCD-chunked
  const int brow = bm * 128;

  // staging: row = (tid>>3) + 32k, chunk c = tid&7 of the 128B row.
  // source chunk pre-XOR'd: csrc = c ^ (row&7) ((row+32k)&7 == (tid>>3)&7).
  // LDS dest linear: tid*16 + k*4096 (rule #21).
  const int csrc = (tid & 7) ^ ((tid >> 3) & 7);
  const u16* gA[4]; const u16* gB[6];
  #pragma unroll
  for (int k = 0; k < 4; ++k)
    gA[k] = A + (size_t)(brow + (tid >> 3) + 32 * k) * 1024 + csrc * 8;
  #pragma unroll
  for (int k = 0; k < 6; ++k)
    gB[k] = Bt + (size_t)(bn * 192 + (tid >> 3) + 32 * k) * 1024 + csrc * 8;

#define ISSUE_ALL(t1) {                                               \
    const size_t ko_ = (size_t)(t1) * 64;                             \
    char* pa_ = smem + ((t1) & 1) * 16384;                            \
    char* pb_ = smem + 32768 + ((t1) & 1) * 24576;                    \
    gload16(gA[0] + ko_, pa_ + tid * 16);                             \
    gload16(gA[1] + ko_, pa_ + tid * 16 + 4096);                      \
    gload16(gA[2] + ko_, pa_ + tid * 16 + 8192);                      \
    gload16(gA[3] + ko_, pa_ + tid * 16 + 12288);                     \
    gload16(gB[0] + ko_, pb_ + tid * 16);                             \
    gload16(gB[1] + ko_, pb_ + tid * 16 + 4096);                      \
    gload16(gB[2] + ko_, pb_ + tid * 16 + 8192);                      \
    gload16(gB[3] + ko_, pb_ + tid * 16 + 12288);                     \
    gload16(gB[4] + ko_, pb_ + tid * 16 + 16384);                     \
    gload16(gB[5] + ko_, pb_ + tid * 16 + 20480); }

  // swizzled read chunk offsets (bytes): chunk = (kk*4+fg) ^ (row&7), row&7 == fr&7
  const int sc0 = ((fg ^ (fr & 7)) << 4);
  const int sc1 = (((4 + fg) ^ (fr & 7)) << 4);

  f32x4 acc[4][6];
  #pragma unroll
  for (int m = 0; m < 4; ++m)
    #pragma unroll
    for (int n = 0; n < 6; ++n) acc[m][n] = (f32x4){0.f, 0.f, 0.f, 0.f};

  ISSUE_ALL(0);
  asm volatile("s_waitcnt vmcnt(0)" ::: "memory");
  __syncthreads();

  for (int t = 0; t < 16; ++t) {
    if (t < 15) ISSUE_ALL(t + 1);
    const char* Ab = smem + (t & 1) * 16384;
    const char* Bb = smem + 32768 + (t & 1) * 24576;
    bf16x8 b0[6], b1[6];
    #pragma unroll
    for (int n = 0; n < 6; ++n) {
      const char* bp = Bb + (wn * 96 + n * 16 + fr) * 128;
      b0[n] = *(const bf16x8*)(bp + sc0);
      b1[n] = *(const bf16x8*)(bp + sc1);
    }
    __builtin_amdgcn_s_setprio(1);
    #pragma unroll
    for (int m = 0; m < 4; ++m) {
      const char* ap = Ab + (wm * 64 + m * 16 + fr) * 128;
      bf16x8 a0 = *(const bf16x8*)(ap + sc0);
      bf16x8 a1 = *(const bf16x8*)(ap + sc1);
      #pragma unroll
      for (int n = 0; n < 6; ++n) {
        acc[m][n] = __builtin_amdgcn_mfma_f32_16x16x32_bf16(a0, b0[n], acc[m][n], 0, 0, 0);
        acc[m][n] = __builtin_amdgcn_mfma_f32_16x16x32_bf16(a1, b1[n], acc[m][n], 0, 0, 0);
      }
    }
    __builtin_amdgcn_s_setprio(0);
    asm volatile("s_waitcnt vmcnt(0)" ::: "memory");
    __syncthreads();
  }

  // ---- epilogue: 2 row-half rounds; 4 slots [64][49] f32; 256 rows/round ----
  float* ldacc = (float*)(smem + 50176);  // [128][4]
  float* fl = (float*)smem;
  #pragma unroll
  for (int rh = 0; rh < 2; ++rh) {
    if (wm == rh) {
      #pragma unroll
      for (int m = 0; m < 4; ++m)
        #pragma unroll
        for (int n = 0; n < 6; ++n) {
          const int g = wn * 2 + (n >= 3 ? 1 : 0);
          const int ci = (n % 3) * 16 + fr;
          #pragma unroll
          for (int q = 0; q < 4; ++q)
            fl[g * 3136 + (m * 16 + fg * 4 + q) * 49 + ci] = acc[m][n][q];
        }
    }
    __syncthreads();
    {
      const int g = tid >> 6, r = tid & 63;
      const float* pr = fl + g * 3136 + r * 49;
      const int grow = brow + rh * 64 + r;
      const int d2 = bn * 4 + g;
      const float* bb = b2 + (size_t)d2 * 47;

      float wv[16], hv[16];
      #pragma unroll
      for (int j = 0; j < 16; ++j) wv[j] = pr[j] + bb[j];
      #pragma unroll
      for (int j = 0; j < 16; ++j) hv[j] = pr[16 + j] + bb[16 + j];

      float x = x2[(size_t)grow * 256 + d2];
      float xc = fminf(fmaxf(x, -3.f), 3.f);

      float mw = wv[0];
      #pragma unroll
      for (int j = 1; j < 16; ++j) mw = fmaxf(mw, wv[j]);
      float sw = 0.f;
      #pragma unroll
      for (int j = 0; j < 16; ++j) { wv[j] = __expf(wv[j] - mw); sw += wv[j]; }
      float scw = 0.984f / sw;

      float mh = hv[0];
      #pragma unroll
      for (int j = 1; j < 16; ++j) mh = fmaxf(mh, hv[j]);
      float sh = 0.f;
      #pragma unroll
      for (int j = 0; j < 16; ++j) { hv[j] = __expf(hv[j] - mh); sh += hv[j]; }
      float sch = 0.984f / sh;

      int idx = 0;
      float xk = -3.f, cum = 0.f;
      #pragma unroll
      for (int i = 1; i <= 15; ++i) {
        cum += 0.001f + wv[i - 1] * scw;
        float cwi = 6.f * cum - 3.f;
        if (xc >= cwi) { idx = i; xk = cwi; }
      }
      float yk = -3.f, cumh = 0.f;
      #pragma unroll
      for (int i = 1; i <= 15; ++i) {
        cumh += 0.001f + hv[i - 1] * sch;
        float chi = 6.f * cumh - 3.f;
        if (i == idx) yk = chi;
      }
      float wk = 1.f, hk = 1.f;
      #pragma unroll
      for (int i = 0; i < 16; ++i) {
        if (i == idx) {
          wk = 6.f * (0.001f + wv[i] * scw);
          hk = 6.f * (0.001f + hv[i] * sch);
        }
      }
      float dk = 1.f, dk1 = 1.f;
      #pragma unroll
      for (int i = 1; i <= 15; ++i) {
        float u = pr[32 + i - 1] + bb[32 + i - 1];
        float e = __expf(u);
        float dd = 0.001f + (u > 15.f ? u : log1pf(e));
        if (i == idx) dk = dd;
        if (i == idx + 1) dk1 = dd;
      }

      float sk = hk / wk;
      float th = (xc - xk) / wk;
      float om = 1.f - th;
      float t1m = th * om;
      float den = sk + (dk + dk1 - 2.f * sk) * t1m;
      float y = yk + hk * (sk * th * th + dk * t1m) / den;
      float deriv = sk * sk * (dk1 * th * th + 2.f * sk * t1m + dk * om * om) / (den * den);
      bool inside = (x > -3.f) && (x < 3.f);
      float yout = inside ? y : x;
      float ld = inside ? __logf(deriv) : 0.f;

      y2[(size_t)grow * 256 + d2] = yout;
      ldacc[(rh * 64 + r) * 4 + g] = ld;
    }
    __syncthreads();
  }

  if (tid < 128) {
    float s = ldacc[tid * 4] + ldacc[tid * 4 + 1] + ldacc[tid * 4 + 2] + ldacc[tid * 4 + 3];
    ldpart[(size_t)bn * 16384 + brow + tid] = s;
  }
}

__global__ void k_reduce_ld(const float* __restrict__ part, float* __restrict__ out) {
  int r = blockIdx.x * 256 + threadIdx.x;
  float s = 0.f;
  for (int j = 0; j < 64; ++j) s += part[(size_t)j * 16384 + r];
  out[r] = s;
}

// ---------------- launch ----------------
extern "C" void kernel_launch(void* const* d_in, const int* in_sizes, int n_in,
                              void* d_out, int out_size, void* d_ws, size_t ws_size,
                              hipStream_t stream) {
  const float* x1 = (const float*)d_in[0];
  const float* x2 = (const float*)d_in[1];
  const float* W0 = (const float*)d_in[2];
  const float* b0 = (const float*)d_in[3];
  const float* W1 = (const float*)d_in[4];
  const float* b1 = (const float*)d_in[5];
  const float* W2 = (const float*)d_in[6];
  const float* b2 = (const float*)d_in[7];
  float* y2 = (float*)d_out;
  float* logdet = y2 + (size_t)16384 * 256;

  char* ws = (char*)d_ws;
  u16* W2t = (u16*)ws;                                   // 25165824
  u16* W0t = (u16*)(ws + 25165824);                      //   524288
  u16* W1t = (u16*)(ws + 25165824 + 524288);             //  2097152
  u16* x1b = (u16*)(ws + 27787264);                      //  8388608
  float* ldp = (float*)(ws + 27787264);                  // aliases x1b (dead by GEMM3); 64*16384*4=4MB
  u16* h1  = (u16*)(ws + 36175872);                      // 33554432
  u16* h2  = (u16*)(ws + 69730304);                      // 33554432

  hipFuncSetAttribute((const void*)k_gemm3_fused,
                      hipFuncAttributeMaxDynamicSharedMemorySize, 81920);

  k_conv_bf16<<<16384, 256, 0, stream>>>(x1, x1b, 16384 * 256);
  k_transconv<<<dim3(8, 32), 256, 0, stream>>>(W0, W0t, 256, 1024, 1024, 0);
  k_transconv<<<dim3(32, 32), 256, 0, stream>>>(W1, W1t, 1024, 1024, 1024, 0);
  k_transconv<<<dim3(32, 384), 256, 0, stream>>>(W2, W2t, 1024, 12032, 12288, 1);

  k_gemm_relu<<<dim3(8, 128), 256, 0, stream>>>(x1b, W0t, b0, h1, 1024, 256);
  k_gemm_relu<<<dim3(8, 128), 256, 0, stream>>>(h1, W1t, b1, h2, 1024, 1024);
  k_gemm3_fused<<<8192, 256, 81920, stream>>>(h2, W2t, b2, x2, y2, ldp);
  k_reduce_ld<<<64, 256, 0, stream>>>(ldp, logdet);
}